// Round 20
// baseline (594.307 us; speedup 1.0000x reference)
//
#include <hip/hip_runtime.h>
#include <hip/hip_bf16.h>
#include <math.h>

#define HW 102400        // 320*320
#define KSEL 4096
#define CAP 16384
#define NB 400

// ---------- helpers ----------
__device__ inline unsigned fkey(float f) {
    unsigned u = __float_as_uint(f);
    return (u & 0x80000000u) ? ~u : (u | 0x80000000u);
}

__device__ inline unsigned wave_sum64_s(unsigned x) {
    x += (unsigned)__builtin_amdgcn_update_dpp(0, (int)x, 0x111, 0xf, 0xf, false);
    x += (unsigned)__builtin_amdgcn_update_dpp(0, (int)x, 0x112, 0xf, 0xf, false);
    x += (unsigned)__builtin_amdgcn_update_dpp(0, (int)x, 0x114, 0xf, 0xf, false);
    x += (unsigned)__builtin_amdgcn_update_dpp(0, (int)x, 0x118, 0xf, 0xf, false);
    x += (unsigned)__builtin_amdgcn_update_dpp(0, (int)x, 0x142, 0xa, 0xf, false);
    x += (unsigned)__builtin_amdgcn_update_dpp(0, (int)x, 0x143, 0xc, 0xf, false);
    return (unsigned)__builtin_amdgcn_readlane((int)x, 63);
}

__device__ inline unsigned long long readlane64(unsigned long long v, int l) {
    unsigned lo = (unsigned)__builtin_amdgcn_readlane((int)(unsigned)(v & 0xffffffffull), l);
    unsigned hi = (unsigned)__builtin_amdgcn_readlane((int)(unsigned)(v >> 32), l);
    return ((unsigned long long)hi << 32) | lo;
}

// device-scope grid barrier: fences make cross-XCD L2 writes visible (G16).
__device__ inline void gridbar(unsigned* slot, unsigned nb) {
    __syncthreads();
    __threadfence();                       // release: flush dirty L2
    if (threadIdx.x == 0) {
        atomicAdd(slot, 1u);
        while (atomicAdd(slot, 0u) < nb) { __builtin_amdgcn_s_sleep(8); }
    }
    __syncthreads();
    __threadfence();                       // acquire: invalidate for remote reads
}

// ---------- K_ALL: fused pipeline ----------
__global__ __launch_bounds__(256, 2) void k_all(
        const float* __restrict__ x, const float* __restrict__ sm,
        float* __restrict__ score, int* __restrict__ clsidx,
        unsigned* __restrict__ hist, unsigned* __restrict__ meta,
        unsigned long long* __restrict__ cand,
        float* __restrict__ topv, float* __restrict__ bl, float* __restrict__ bt,
        float* __restrict__ br, float* __restrict__ bb, float* __restrict__ area,
        int* __restrict__ clsk, unsigned long long* __restrict__ mask,
        const float* __restrict__ padding, const float* __restrict__ ratio,
        const int* __restrict__ piw, const int* __restrict__ pih,
        float* __restrict__ out) {
    __shared__ __align__(16) char smem[69632];   // 68KB union -> 2 blocks/CU
    const int t = threadIdx.x;
    const int b = blockIdx.x;
    unsigned* bar = meta + 8;                    // 4 barrier slots, memset-zeroed

    // ================= Phase A: score + argmax + hist (r8-proven) =================
    {
        float (*swt)[16] = (float(*)[16])smem;                 // 16KB
        float (*tile)[16][256] = (float(*)[16][256])(smem + 16384);  // 32KB
        for (int i = t; i < 4096; i += 256) {
            int k = i >> 8, c = i & 255;
            swt[c][k] = sm[i];
        }
        int wave = t >> 6, lane = t & 63;
        size_t pxb = (size_t)b * 256;
        const float* xc = x + (size_t)5 * HW + pxb;

        float acc[16];
#pragma unroll
        for (int k = 0; k < 16; ++k) acc[k] = 0.f;
        float4 sa[4], sb[4];

#define LOADX(dst, ti)                                                         \
    _Pragma("unroll") for (int j = 0; j < 4; ++j)                              \
        dst[j] = *(const float4*)(xc + (size_t)((ti) * 16 + wave * 4 + j) * HW + lane * 4);
#define STOREX(src, s)                                                         \
    _Pragma("unroll") for (int j = 0; j < 4; ++j)                              \
        ((float4*)&tile[s][wave * 4 + j][0])[lane] = src[j];
#define COMP(s, ti)                                                            \
    _Pragma("unroll") for (int cc = 0; cc < 16; ++cc) {                        \
        float xv = tile[s][cc][t];                                             \
        const float4* w4 = (const float4*)&swt[(ti) * 16 + cc][0];             \
        float4 w0 = w4[0], w1 = w4[1], w2 = w4[2], w3 = w4[3];                 \
        acc[0]  = fmaf(xv, w0.x, acc[0]);  acc[1]  = fmaf(xv, w0.y, acc[1]);   \
        acc[2]  = fmaf(xv, w0.z, acc[2]);  acc[3]  = fmaf(xv, w0.w, acc[3]);   \
        acc[4]  = fmaf(xv, w1.x, acc[4]);  acc[5]  = fmaf(xv, w1.y, acc[5]);   \
        acc[6]  = fmaf(xv, w1.z, acc[6]);  acc[7]  = fmaf(xv, w1.w, acc[7]);   \
        acc[8]  = fmaf(xv, w2.x, acc[8]);  acc[9]  = fmaf(xv, w2.y, acc[9]);   \
        acc[10] = fmaf(xv, w2.z, acc[10]); acc[11] = fmaf(xv, w2.w, acc[11]);  \
        acc[12] = fmaf(xv, w3.x, acc[12]); acc[13] = fmaf(xv, w3.y, acc[13]);  \
        acc[14] = fmaf(xv, w3.z, acc[14]); acc[15] = fmaf(xv, w3.w, acc[15]);  \
    }
        LOADX(sa, 0);
        STOREX(sa, 0);
        LOADX(sa, 1);
        LOADX(sb, 2);
        __syncthreads();
#pragma unroll
        for (int k = 0; k < 16; k += 2) {
            COMP(k & 1, k);
            STOREX(sa, (k + 1) & 1);
            if (k + 3 < 16) LOADX(sa, k + 3);
            __syncthreads();
            COMP((k + 1) & 1, k + 1);
            if (k + 2 < 16) { STOREX(sb, k & 1); }
            if (k + 4 < 16) LOADX(sb, k + 4);
            __syncthreads();
        }
#undef LOADX
#undef STOREX
#undef COMP
        float mv = acc[0]; int mi = 0;
#pragma unroll
        for (int k = 1; k < 16; ++k)
            if (acc[k] > mv) { mv = acc[k]; mi = k; }
        int n = (int)pxb + t;
        float x0 = x[n];
        float sig = 1.0f / (1.0f + expf(-x0));
        float sc = (sig > 0.5f) ? sig * mv : -INFINITY;
        score[n] = sc;
        clsidx[n] = mi;
        if (sc != -INFINITY) atomicAdd(&hist[fkey(sc) >> 16], 1u);
    }
    gridbar(&bar[0], NB);

    // ================= Phase B: per-block redundant p16 =================
    unsigned p16;
    {
        unsigned* part = (unsigned*)smem;              // 256 u32
        unsigned* shr  = (unsigned*)(smem + 1024);     // [0]=g [1]=s_after [2]=p16
        if (t == 0) { shr[0] = 0; shr[1] = 0; }
        unsigned s = 0;
        const uint4* hp4 = (const uint4*)(hist + (size_t)t * 256);
#pragma unroll 8
        for (int i = 0; i < 64; ++i) { uint4 v = hp4[i]; s += v.x + v.y + v.z + v.w; }
        part[t] = s;
        __syncthreads();
        for (int off = 1; off < 256; off <<= 1) {
            unsigned v = (t + off < 256) ? part[t + off] : 0u;
            __syncthreads();
            part[t] += v;
            __syncthreads();
        }
        if (part[t] >= KSEL && (t == 255 || part[t + 1] < KSEL)) {
            shr[0] = (unsigned)t;
            shr[1] = (t == 255) ? 0u : part[t + 1];
        }
        __syncthreads();
        if (t == 0) {
            unsigned g = shr[0], acc = shr[1], p = g * 256;
            for (int b2 = 255; b2 >= 0; --b2) {
                acc += hist[g * 256 + b2];
                if (acc >= KSEL) { p = g * 256 + (unsigned)b2; break; }
            }
            shr[2] = p;
        }
        __syncthreads();
        p16 = shr[2];
        __syncthreads();
    }

    // ================= Phase C: collect (own pixels) =================
    {
        int n = b * 256 + t;
        unsigned key = fkey(score[n]);
        if ((key >> 16) >= p16) {
            unsigned pos = atomicAdd(&meta[0], 1u);
            if (pos < CAP)
                cand[pos] = ((unsigned long long)key << 32) | (unsigned)(~(unsigned)n);
        }
    }
    gridbar(&bar[1], NB);

    // ================= Phase D: rank + gather (blocks 0..63) =================
    if (b < 64) {
        unsigned long long* tile64 = (unsigned long long*)smem;   // 8KB
        int C = (int)meta[0]; if (C > CAP) C = CAP;
        int j = b * 256 + t;
        unsigned long long kj = (j < C) ? cand[j] : 0ull;
        unsigned rank = 0;
        for (int tb = 0; tb < C; tb += 1024) {
            int cnt = min(1024, C - tb);
            __syncthreads();
            for (int u = t; u < cnt; u += 256) tile64[u] = cand[tb + u];
            __syncthreads();
            if (j < C)
                for (int u = 0; u < cnt; ++u) rank += (tile64[u] > kj) ? 1u : 0u;
        }
        if (j < C && rank < KSEL) {
            unsigned n = ~(unsigned)(kj & 0xFFFFFFFFull);
            float l  = x[(size_t)1 * HW + n];
            float tt = x[(size_t)2 * HW + n];
            float r  = x[(size_t)3 * HW + n];
            float bo = x[(size_t)4 * HW + n];
            topv[rank] = score[n];
            bl[rank] = l; bt[rank] = tt; br[rank] = r; bb[rank] = bo;
            area[rank] = (r - l) * (bo - tt);
            clsk[rank] = clsidx[n];
        }
    }
    gridbar(&bar[2], NB);

    // ================= Phase E: IoU mask (blocks 0..255) =================
    if (b < 256) {
        float* sl = (float*)smem;            // 5 x 1KB
        float* stt = (float*)(smem + 1024);
        float* sr = (float*)(smem + 2048);
        float* sbb = (float*)(smem + 3072);
        float* saa = (float*)(smem + 4096);
        int ic = b >> 4;
        int jc = b & 15;
        int i = ic * 256 + t;
        int j0 = jc * 256;
        sl[t] = bl[j0 + t]; stt[t] = bt[j0 + t]; sr[t] = br[j0 + t];
        sbb[t] = bb[j0 + t]; saa[t] = area[j0 + t];
        __syncthreads();
        float li = bl[i], ti = bt[i], ri = br[i], bi = bb[i], ai = area[i];
#pragma unroll
        for (int w = 0; w < 4; ++w) {
            unsigned long long m = 0;
            for (int k2 = 0; k2 < 64; ++k2) {
                int j = w * 64 + k2;
                float iw = fminf(ri, sr[j]) - fmaxf(li, sl[j]); iw = fmaxf(iw, 0.f);
                float ih = fminf(bi, sbb[j]) - fmaxf(ti, stt[j]); ih = fmaxf(ih, 0.f);
                float inter = iw * ih;
                float uni = ai + saa[j] - inter + 1e-10f;
                if (inter / uni >= 0.2f) m |= (1ull << k2);
            }
            mask[(size_t)i * 64 + (jc * 4 + w)] = m;
        }
        __syncthreads();
    }
    gridbar(&bar[3], NB);
    if (b != 0) return;

    // ================= Phase F: NMS (r10-proven, 102us) + epilogue, block 0 =================
    {
        unsigned long long* rowsF = (unsigned long long*)smem;          // [2][4096] = 64KB
        unsigned long long* aliveL = (unsigned long long*)(smem + 65536);  // 64
        unsigned long long* keptL  = (unsigned long long*)(smem + 66048);  // 64
        unsigned* cntF = (unsigned*)(smem + 66560);                        // 64
        int lane = t & 63;
        int W = t >> 6;
        int g = t & 3;
        int jrow = t >> 2;

#define STAGEF(bb2, s)                                                          \
    do {                                                                        \
        _Pragma("unroll") for (int i_ = 0; i_ < 8; ++i_) {                      \
            int seg_ = i_ * 4 + W;                                              \
            int r_ = seg_ * 2 + (lane >> 5);                                    \
            int p_ = (lane & 31) * 2;                                           \
            int wl_ = (p_ - 2 * r_) & 63;                                       \
            const unsigned long long* gp_ =                                     \
                mask + ((size_t)((bb2) * 64 + r_) * 64 + wl_);                  \
            __builtin_amdgcn_global_load_lds(                                   \
                (const __attribute__((address_space(1))) void*)gp_,             \
                (__attribute__((address_space(3))) void*)&rowsF[(s) * 4096 + seg_ * 128], \
                16, 0, 0);                                                      \
        }                                                                       \
    } while (0)

#define VERF(jj, rw)                                                            \
    {                                                                           \
        unsigned long long awc = readlane64(alive, bq);                         \
        if ((awc >> (jj)) & 1ull) {                                             \
            unsigned long long awAdj = alive;                                   \
            unsigned long long pm = ((jj) == 63) ? ~0ull                        \
                                                 : ((1ull << ((jj) + 1)) - 1ull); \
            if (lane == bq) awAdj &= ~pm;                                       \
            unsigned c_ = (unsigned)__popcll((rw) & awAdj);                     \
            unsigned tt_ = wave_sum64_s(c_);                                    \
            if (tt_ >= 10u) { alive &= ~(rw); keptB |= 1ull << (jj); }          \
        }                                                                       \
    }

        STAGEF(0, 0);
        STAGEF(1, 1);

        unsigned long long alive = 0, areaok = 0, keptAcc = 0;
        if (W == 0) {
            for (int k = 0; k < 64; ++k) {
                float tv = topv[(size_t)k * 64 + lane];
                float ar = area[(size_t)k * 64 + lane];
                unsigned long long b1 = __ballot(tv != -INFINITY);
                unsigned long long b2 = __ballot(ar >= 4.0f);
                if (lane == k) { alive = b1; areaok = b2; }
            }
            aliveL[lane] = alive;
        }

        for (int bq = 0; bq < 64; ++bq) {
            if (bq < 63) asm volatile("s_waitcnt vmcnt(8)" ::: "memory");
            else         asm volatile("s_waitcnt vmcnt(0)" ::: "memory");
            __builtin_amdgcn_sched_barrier(0);
            __builtin_amdgcn_s_barrier();            // B1

            const unsigned long long* rb = &rowsF[(bq & 1) * 4096];

            unsigned long long pfxj = (jrow == 63) ? ~0ull : ((1ull << (jrow + 1)) - 1ull);
            int base_w = g * 16;
            unsigned cnt = 0;
#pragma unroll
            for (int q = 0; q < 8; ++q) {
                int wl = base_w + q * 2;
                int ph = (wl + 2 * jrow) & 63;
                ulonglong2 rv = *(const ulonglong2*)&rb[jrow * 64 + ph];
                ulonglong2 av = *(const ulonglong2*)&aliveL[wl];
                unsigned cx = (unsigned)__popcll(rv.x & av.x);
                unsigned cy = (unsigned)__popcll(rv.y & av.y);
                cnt += cx + cy;
                if (wl == bq)     cnt -= (unsigned)__popcll(rv.x & av.x & pfxj);
                if (wl + 1 == bq) cnt -= (unsigned)__popcll(rv.y & av.y & pfxj);
            }
            cnt += (unsigned)__builtin_amdgcn_update_dpp(0, (int)cnt, 0xB1, 0xf, 0xf, false);
            cnt += (unsigned)__builtin_amdgcn_update_dpp(0, (int)cnt, 0x4E, 0xf, 0xf, false);
            if (g == 0) cntF[jrow] = cnt;
            asm volatile("s_waitcnt lgkmcnt(0)" ::: "memory");
            __builtin_amdgcn_s_barrier();            // B2

            if (W == 0) {
                unsigned long long keptB = 0;
                unsigned long long aw0snap = readlane64(alive, bq);
                unsigned long long areaok0 = readlane64(areaok, bq);
                unsigned myc = cntF[lane];
                bool candp = (myc >= 10u) && ((areaok0 >> lane) & 1ull) &&
                             ((aw0snap >> lane) & 1ull);
                unsigned long long cq = __ballot(candp);
                while (cq) {
                    int j1 = __ffsll(cq) - 1; cq &= cq - 1;
                    int j2 = -1, j3 = -1, j4 = -1;
                    if (cq) { j2 = __ffsll(cq) - 1; cq &= cq - 1; }
                    if (cq) { j3 = __ffsll(cq) - 1; cq &= cq - 1; }
                    if (cq) { j4 = __ffsll(cq) - 1; cq &= cq - 1; }
                    unsigned long long r1 = rb[j1 * 64 + ((lane + 2 * j1) & 63)];
                    unsigned long long r2 = (j2 >= 0) ? rb[j2 * 64 + ((lane + 2 * j2) & 63)] : 0;
                    unsigned long long r3 = (j3 >= 0) ? rb[j3 * 64 + ((lane + 2 * j3) & 63)] : 0;
                    unsigned long long r4 = (j4 >= 0) ? rb[j4 * 64 + ((lane + 2 * j4) & 63)] : 0;
                    VERF(j1, r1);
                    if (j2 >= 0) VERF(j2, r2);
                    if (j3 >= 0) VERF(j3, r3);
                    if (j4 >= 0) VERF(j4, r4);
                }
                if (lane == bq) { alive = 0; keptAcc = keptB; }
                aliveL[lane] = alive;
            }
            asm volatile("s_waitcnt lgkmcnt(0)" ::: "memory");
            __builtin_amdgcn_s_barrier();            // B3
            if (bq + 2 < 64) STAGEF(bq + 2, bq & 1);
        }
        if (W == 0) keptL[lane] = keptAcc;
        __syncthreads();

        // epilogue
        float p0 = padding[0], p1 = padding[1];
        float invr = 1.0f / ratio[0];
        float Wimg = (float)piw[0], Himg = (float)pih[0];
        for (int i = t; i < KSEL; i += 256) {
            bool kept = (keptL[i >> 6] >> (i & 63)) & 1ull;
            float tv = topv[i];
            bool keep = kept && (tv >= 0.5f);
            float x1 = fmaxf((bl[i] - p0) * invr, 0.f);
            float y1 = fmaxf((bt[i] - p1) * invr, 0.f);
            float x2 = fminf((br[i] - p0) * invr, Wimg);
            float y2 = fminf((bb[i] - p1) * invr, Himg);
            keep = keep && (x1 < Wimg) && (y1 < Himg);
            float* o = out + (size_t)i * 7;
            if (keep) {
                o[0] = 1.0f; o[1] = tv; o[2] = x1; o[3] = y1; o[4] = x2; o[5] = y2;
                o[6] = (float)clsk[i];
            } else {
                o[0] = 0.f; o[1] = 0.f; o[2] = 0.f; o[3] = 0.f; o[4] = 0.f; o[5] = 0.f; o[6] = 0.f;
            }
        }
#undef STAGEF
#undef VERF
    }
}

extern "C" void kernel_launch(void* const* d_in, const int* in_sizes, int n_in,
                              void* d_out, int out_size, void* d_ws, size_t ws_size,
                              hipStream_t stream) {
    const float* x       = (const float*)d_in[0];
    const float* sm      = (const float*)d_in[1];
    const float* padding = (const float*)d_in[2];
    const float* ratio   = (const float*)d_in[3];
    const int*   piw     = (const int*)d_in[4];
    const int*   pih     = (const int*)d_in[5];
    float* out = (float*)d_out;
    char* ws = (char*)d_ws;

    // workspace layout (bytes)
    float* score               = (float*)(ws + 0);                 // 409600
    int*   clsidx              = (int*)(ws + 409600);              // 409600
    unsigned* hist             = (unsigned*)(ws + 819200);         // 262144
    unsigned* meta             = (unsigned*)(ws + 1081344);        // 512: [0]=cnt, [8..11]=barriers
    unsigned long long* cand   = (unsigned long long*)(ws + 1081856); // 131072
    float* topv                = (float*)(ws + 1212928);           // 16384
    float* bl                  = (float*)(ws + 1229312);
    float* bt                  = (float*)(ws + 1245696);
    float* br                  = (float*)(ws + 1262080);
    float* bb                  = (float*)(ws + 1278464);
    float* area                = (float*)(ws + 1294848);
    int*   clsk                = (int*)(ws + 1311232);
    unsigned long long* mask   = (unsigned long long*)(ws + 1328128); // 2097152

    hipMemsetAsync(hist, 0, 262144 + 512, stream);  // hist + meta (incl. barriers)

    k_all<<<NB, 256, 0, stream>>>(x, sm, score, clsidx, hist, meta, cand,
                                  topv, bl, bt, br, bb, area, clsk, mask,
                                  padding, ratio, piw, pih, out);
}